// Round 1
// baseline (321.127 us; speedup 1.0000x reference)
//
#include <hip/hip_runtime.h>

typedef unsigned short u16;
typedef __bf16 bf16x8 __attribute__((ext_vector_type(8)));
typedef float f32x4 __attribute__((ext_vector_type(4)));

#define NB 8
#define NC 512
#define NHD 8
#define DH 64
#define NN 1024

// ---- fp32 -> bf16 split helpers (RNE) ----
__device__ __forceinline__ u16 f2bf(float f) {
    union { float f; unsigned u; } v; v.f = f;
    unsigned r = v.u + 0x7fffu + ((v.u >> 16) & 1u);
    return (u16)(r >> 16);
}
__device__ __forceinline__ float bf2f(u16 h) {
    union { unsigned u; float f; } v; v.u = ((unsigned)h) << 16;
    return v.f;
}

// ================= kernel 1: split a dense fp32 array into bf16 hi/lo =================
__global__ __launch_bounds__(256) void k_split(const float* __restrict__ src,
                                               u16* __restrict__ hi, u16* __restrict__ lo, int n) {
    int i = blockIdx.x * 256 + threadIdx.x;
    if (i < n) {
        float f = src[i];
        u16 h = f2bf(f);
        hi[i] = h;
        lo[i] = f2bf(f - bf2f(h));
    }
}

// ================= kernel 2: pos[h, i, d] = rel_h + rel_w, transposed + split =================
__global__ __launch_bounds__(256) void k_pos(const float* __restrict__ relh, const float* __restrict__ relw,
                                             u16* __restrict__ phi, u16* __restrict__ plo) {
    int idx = blockIdx.x * 256 + threadIdx.x;   // HEADS*N*DH = 524288 threads
    int dd = idx & 63;
    int i  = (idx >> 6) & 1023;
    int h  = idx >> 16;
    float f = relh[(h * 64 + dd) * 32 + (i & 31)] + relw[(h * 64 + dd) * 32 + (i >> 5)];
    u16 hb = f2bf(f);
    int o = (h * 1024 + i) * 64 + dd;
    phi[o] = hb;
    plo[o] = f2bf(f - bf2f(hb));
}

// ================= kernel 3: transpose x[b,c,n] -> xt[b,n,c] with bf16 hi/lo split =================
__global__ __launch_bounds__(256) void k_tsplit(const float* __restrict__ x, const float* __restrict__ d,
                                                u16* __restrict__ xhi, u16* __restrict__ xlo,
                                                u16* __restrict__ dhi, u16* __restrict__ dlo) {
    __shared__ float tile[64][65];
    int nb = blockIdx.x * 64;
    int cb = blockIdx.y * 64;
    int b = blockIdx.z & 7;
    int which = blockIdx.z >> 3;
    const float* src = which ? d : x;
    u16* ohi = which ? dhi : xhi;
    u16* olo = which ? dlo : xlo;
    int t = threadIdx.x;
    // load: 64 c-rows x 64 n-cols, coalesced along n
    {
        int crow = t >> 2, n0 = (t & 3) * 16;
        const float* g = src + ((size_t)(b * NC + cb + crow)) * NN + nb + n0;
#pragma unroll
        for (int k = 0; k < 16; k += 4) {
            float4 v = *(const float4*)(g + k);
            tile[crow][n0 + k + 0] = v.x;
            tile[crow][n0 + k + 1] = v.y;
            tile[crow][n0 + k + 2] = v.z;
            tile[crow][n0 + k + 3] = v.w;
        }
    }
    __syncthreads();
    // store: 64 n-rows x 64 c-cols, coalesced along c
    {
        int nrow = t >> 2, c0 = (t & 3) * 16;
        union { u16 s[16]; uint4 v[2]; } uh, ul;
#pragma unroll
        for (int k = 0; k < 16; ++k) {
            float f = tile[c0 + k][nrow];
            u16 hb = f2bf(f);
            uh.s[k] = hb;
            ul.s[k] = f2bf(f - bf2f(hb));
        }
        size_t oidx = ((size_t)(b * NN + nb + nrow)) * NC + cb + c0;
        *(uint4*)(ohi + oidx)     = uh.v[0];
        *(uint4*)(ohi + oidx + 8) = uh.v[1];
        *(uint4*)(olo + oidx)     = ul.v[0];
        *(uint4*)(olo + oidx + 8) = ul.v[1];
    }
}

// ================= kernel 4: projection GEMM (split-bf16, 128x128 tile) =================
// q/k: 3 passes (Whi*Xhi + Wlo*Xhi + Whi*Xlo), epilogue -> transposed [b,h,n,d] hi/lo
// v:   1 pass  (Whi*Xhi), epilogue -> natural [b,h,d,n] bf16
__global__ __launch_bounds__(256) void k_proj(
    const u16* __restrict__ xt_hi, const u16* __restrict__ xt_lo,
    const u16* __restrict__ dt_hi, const u16* __restrict__ dt_lo,
    const u16* __restrict__ wq_hi, const u16* __restrict__ wq_lo,
    const u16* __restrict__ wk_hi, const u16* __restrict__ wk_lo,
    const u16* __restrict__ wv_hi,
    const float* __restrict__ bq, const float* __restrict__ bk, const float* __restrict__ bv,
    u16* __restrict__ qt_hi, u16* __restrict__ qt_lo,
    u16* __restrict__ kt_hi, u16* __restrict__ kt_lo,
    u16* __restrict__ v_out) {
    __shared__ u16 Asm[128 * 40];
    __shared__ u16 Bsm[128 * 40];

    int p = blockIdx.z % 3;
    int b = blockIdx.z / 3;
    const u16 *Whi, *Wlo, *Xhi, *Xlo;
    const float* bias;
    u16 *Ohi, *Olo;
    int segs;
    if (p == 0)      { Whi = wq_hi; Wlo = wq_lo; Xhi = xt_hi; Xlo = xt_lo; bias = bq; Ohi = qt_hi; Olo = qt_lo; segs = 3; }
    else if (p == 1) { Whi = wk_hi; Wlo = wk_lo; Xhi = dt_hi; Xlo = dt_lo; bias = bk; Ohi = kt_hi; Olo = kt_lo; segs = 3; }
    else             { Whi = wv_hi; Wlo = wv_hi; Xhi = dt_hi; Xlo = dt_hi; bias = bv; Ohi = v_out; Olo = v_out; segs = 1; }

    int obase = blockIdx.x * 128;
    int nbase = blockIdx.y * 128;
    int t = threadIdx.x, wave = t >> 6, lane = t & 63, quad = lane >> 4, l15 = lane & 15;
    int wr = (wave >> 1) * 64, wc = (wave & 1) * 64;

    f32x4 acc[4][4];
#pragma unroll
    for (int fo = 0; fo < 4; ++fo)
#pragma unroll
        for (int fn = 0; fn < 4; ++fn)
#pragma unroll
            for (int r = 0; r < 4; ++r) acc[fo][fn][r] = 0.f;

    for (int s = 0; s < segs; ++s) {
        const u16* Ap = (s == 1) ? Wlo : Whi;
        const u16* Bp = ((s == 2) ? Xlo : Xhi) + (size_t)b * NN * NC;
        for (int kk = 0; kk < NC; kk += 32) {
            __syncthreads();
#pragma unroll
            for (int hh = 0; hh < 2; ++hh) {
                int chunk = t + hh * 256;            // 512 chunks of 8 bf16
                int row = chunk >> 2, cc = (chunk & 3) * 8;
                *(uint4*)&Asm[row * 40 + cc] = *(const uint4*)&Ap[(size_t)(obase + row) * NC + kk + cc];
                *(uint4*)&Bsm[row * 40 + cc] = *(const uint4*)&Bp[(size_t)(nbase + row) * NC + kk + cc];
            }
            __syncthreads();
            bf16x8 af[4], bfr[4];
#pragma unroll
            for (int fo = 0; fo < 4; ++fo) af[fo] = *(const bf16x8*)&Asm[(wr + fo * 16 + l15) * 40 + quad * 8];
#pragma unroll
            for (int fn = 0; fn < 4; ++fn) bfr[fn] = *(const bf16x8*)&Bsm[(wc + fn * 16 + l15) * 40 + quad * 8];
#pragma unroll
            for (int fo = 0; fo < 4; ++fo)
#pragma unroll
                for (int fn = 0; fn < 4; ++fn)
                    acc[fo][fn] = __builtin_amdgcn_mfma_f32_16x16x32_bf16(af[fo], bfr[fn], acc[fo][fn], 0, 0, 0);
        }
    }

    // epilogue
#pragma unroll
    for (int fo = 0; fo < 4; ++fo) {
#pragma unroll
        for (int fn = 0; fn < 4; ++fn) {
            int o0 = obase + wr + fo * 16 + quad * 4;     // 4-aligned, never crosses a head
            int n = nbase + wc + fn * 16 + l15;
            if (p < 2) {
                union { u16 s[4]; uint2 v2; } uh, ul;
#pragma unroll
                for (int r = 0; r < 4; ++r) {
                    int o = o0 + r;
                    float val = acc[fo][fn][r] + bias[o];
                    u16 hb = f2bf(val);
                    uh.s[r] = hb;
                    ul.s[r] = f2bf(val - bf2f(hb));
                }
                int head = o0 >> 6, dd0 = o0 & 63;
                size_t idx = (((size_t)(b * NHD + head) * NN) + n) * DH + dd0;
                *(uint2*)&Ohi[idx] = uh.v2;
                *(uint2*)&Olo[idx] = ul.v2;
            } else {
#pragma unroll
                for (int r = 0; r < 4; ++r) {
                    int o = o0 + r;
                    float val = acc[fo][fn][r] + bias[o];
                    int head = o >> 6, dd = o & 63;
                    Ohi[((size_t)(b * NHD + head) * DH + dd) * NN + n] = f2bf(val);
                }
            }
        }
    }
}

// ================= kernel 5: fused flash attention =================
// block = (iblock of 64 queries, head, batch). j-chunks of 32, online softmax.
// S = [Q;Pos]^T [K;Q] with extended inner dim 128, split-bf16 3-pass.
__global__ __launch_bounds__(256) void k_attn(
    const u16* __restrict__ qt_hi, const u16* __restrict__ qt_lo,
    const u16* __restrict__ kt_hi, const u16* __restrict__ kt_lo,
    const u16* __restrict__ v_, const u16* __restrict__ post_hi, const u16* __restrict__ post_lo,
    float* __restrict__ out) {
    __shared__ u16 Ah[64 * 136];
    __shared__ u16 Al[64 * 136];
    __shared__ u16 Bh[32 * 136];
    __shared__ u16 Bl[32 * 136];
    __shared__ u16 Vt[64 * 40];
    __shared__ u16 Pt[64 * 40];
    __shared__ float alpha_s[64];
    __shared__ float l_s[64];

    int ib = blockIdx.x, h = blockIdx.y, b = blockIdx.z;
    int t = threadIdx.x, wave = t >> 6, lane = t & 63, quad = lane >> 4, l15 = lane & 15;
    size_t bh = (size_t)(b * NHD + h);
    const u16* qh = qt_hi + bh * NN * DH;
    const u16* ql = qt_lo + bh * NN * DH;
    const u16* kh = kt_hi + bh * NN * DH;
    const u16* kl = kt_lo + bh * NN * DH;
    const u16* vv = v_ + bh * DH * NN;
    const u16* ph = post_hi + (size_t)h * NN * DH;
    const u16* pl = post_lo + (size_t)h * NN * DH;
    int i0 = ib * 64;

    // stage A tile (rows i=0..64, cols ke=0..128: [Q | Pos]), hi and lo
#pragma unroll
    for (int u = 0; u < 8; ++u) {
        int cid = u * 256 + t;          // 2048 16B chunks
        int arr = cid >> 10;
        int rem = cid & 1023;
        int row = rem >> 4;
        int cc = (rem & 15) * 8;
        const u16* src;
        if (cc < 64) src = (arr ? ql : qh) + (size_t)(i0 + row) * DH + cc;
        else         src = (arr ? pl : ph) + (size_t)(i0 + row) * DH + (cc - 64);
        *(uint4*)((arr ? Al : Ah) + row * 136 + cc) = *(const uint4*)src;
    }

    float m_[4], l_[4];
#pragma unroll
    for (int r = 0; r < 4; ++r) { m_[r] = -__builtin_inff(); l_[r] = 0.f; }
    f32x4 oacc[4];
#pragma unroll
    for (int f = 0; f < 4; ++f)
#pragma unroll
        for (int r = 0; r < 4; ++r) oacc[f][r] = 0.f;

    for (int jc = 0; jc < NN; jc += 32) {
        __syncthreads();   // prev-iter PV reads done before restaging
        // stage B tile (rows j=0..32, cols [K | Q]) hi+lo, and V tile [d][j]
#pragma unroll
        for (int u = 0; u < 4; ++u) {
            int cid = u * 256 + t;      // 1024 chunks
            int arr = cid >> 9;
            int rem = cid & 511;
            int row = rem >> 4;
            int cc = (rem & 15) * 8;
            const u16* src;
            if (cc < 64) src = (arr ? kl : kh) + (size_t)(jc + row) * DH + cc;
            else         src = (arr ? ql : qh) + (size_t)(jc + row) * DH + (cc - 64);
            *(uint4*)((arr ? Bl : Bh) + row * 136 + cc) = *(const uint4*)src;
        }
        {
            int drow = t >> 2, cc = (t & 3) * 8;
            *(uint4*)(Vt + drow * 40 + cc) = *(const uint4*)(vv + (size_t)drow * NN + jc + cc);
        }
        __syncthreads();

        // ---- S phase: wave owns i-strip [16*wave, 16*wave+16) ----
        f32x4 sacc[2];
#pragma unroll
        for (int jf = 0; jf < 2; ++jf)
#pragma unroll
            for (int r = 0; r < 4; ++r) sacc[jf][r] = 0.f;
#pragma unroll
        for (int pass = 0; pass < 3; ++pass) {
            const u16* Ab = (pass == 1) ? Al : Ah;
            const u16* Bb = (pass == 2) ? Bl : Bh;
#pragma unroll
            for (int ks = 0; ks < 4; ++ks) {
                bf16x8 af = *(const bf16x8*)(Ab + (wave * 16 + l15) * 136 + ks * 32 + quad * 8);
                bf16x8 b0 = *(const bf16x8*)(Bb + (l15) * 136 + ks * 32 + quad * 8);
                bf16x8 b1 = *(const bf16x8*)(Bb + (16 + l15) * 136 + ks * 32 + quad * 8);
                sacc[0] = __builtin_amdgcn_mfma_f32_16x16x32_bf16(af, b0, sacc[0], 0, 0, 0);
                sacc[1] = __builtin_amdgcn_mfma_f32_16x16x32_bf16(af, b1, sacc[1], 0, 0, 0);
            }
        }

        // ---- online softmax (rows i = wave*16 + quad*4 + r; 16 lanes per quad share rows) ----
        float mc[4];
#pragma unroll
        for (int r = 0; r < 4; ++r) mc[r] = fmaxf(sacc[0][r], sacc[1][r]);
#pragma unroll
        for (int off = 8; off; off >>= 1)
#pragma unroll
            for (int r = 0; r < 4; ++r) mc[r] = fmaxf(mc[r], __shfl_xor(mc[r], off));
        float al[4], ps[4];
#pragma unroll
        for (int r = 0; r < 4; ++r) {
            float mn = fmaxf(m_[r], mc[r]);
            al[r] = __expf(m_[r] - mn);
            m_[r] = mn;
            float p0 = __expf(sacc[0][r] - mn);
            float p1 = __expf(sacc[1][r] - mn);
            ps[r] = p0 + p1;
            int irow = wave * 16 + quad * 4 + r;
            Pt[irow * 40 + l15] = f2bf(p0);
            Pt[irow * 40 + 16 + l15] = f2bf(p1);
        }
#pragma unroll
        for (int off = 8; off; off >>= 1)
#pragma unroll
            for (int r = 0; r < 4; ++r) ps[r] += __shfl_xor(ps[r], off);
#pragma unroll
        for (int r = 0; r < 4; ++r) l_[r] = l_[r] * al[r] + ps[r];
        if (l15 == 0) {
#pragma unroll
            for (int r = 0; r < 4; ++r) alpha_s[wave * 16 + quad * 4 + r] = al[r];
        }
        __syncthreads();

        // ---- PV phase: wave owns d-strip [16*wave, 16*wave+16) ----
        bf16x8 vf = *(const bf16x8*)(Vt + (wave * 16 + l15) * 40 + quad * 8);
#pragma unroll
        for (int ifr = 0; ifr < 4; ++ifr) {
            float av = alpha_s[ifr * 16 + l15];
#pragma unroll
            for (int r = 0; r < 4; ++r) oacc[ifr][r] *= av;
            bf16x8 pf = *(const bf16x8*)(Pt + (ifr * 16 + l15) * 40 + quad * 8);
            oacc[ifr] = __builtin_amdgcn_mfma_f32_16x16x32_bf16(vf, pf, oacc[ifr], 0, 0, 0);
        }
    }

    if (l15 == 0) {
#pragma unroll
        for (int r = 0; r < 4; ++r) l_s[wave * 16 + quad * 4 + r] = l_[r];
    }
    __syncthreads();
#pragma unroll
    for (int ifr = 0; ifr < 4; ++ifr) {
        float li = 1.0f / l_s[ifr * 16 + l15];
#pragma unroll
        for (int r = 0; r < 4; ++r) {
            int dd = wave * 16 + quad * 4 + r;
            out[((size_t)b * NC + h * DH + dd) * NN + i0 + ifr * 16 + l15] = oacc[ifr][r] * li;
        }
    }
}

// ================= workspace layout (bytes) =================
#define SXT  (8u * 1024u * 512u * 2u)      /* 8388608: one [B,N,C] bf16 array */
#define SW   (512u * 512u * 2u)            /* 524288 */
#define SQT  SXT                            /* [B,H,N,DH] bf16 == same size */
#define SPOS (8u * 1024u * 64u * 2u)       /* 1048576 */

#define OFF_XT_HI  (0u)
#define OFF_XT_LO  (OFF_XT_HI + SXT)
#define OFF_DT_HI  (OFF_XT_LO + SXT)
#define OFF_DT_LO  (OFF_DT_HI + SXT)
#define OFF_WQ_HI  (OFF_DT_LO + SXT)
#define OFF_WQ_LO  (OFF_WQ_HI + SW)
#define OFF_WK_HI  (OFF_WQ_LO + SW)
#define OFF_WK_LO  (OFF_WK_HI + SW)
#define OFF_WV_HI  (OFF_WK_LO + SW)
#define OFF_WV_LO  (OFF_WV_HI + SW)
#define OFF_QT_HI  (OFF_WV_LO + SW)
#define OFF_QT_LO  (OFF_QT_HI + SQT)
#define OFF_KT_HI  (OFF_QT_LO + SQT)
#define OFF_KT_LO  (OFF_KT_HI + SQT)
#define OFF_V     (OFF_KT_LO + SQT)
#define OFF_POS_HI (OFF_V + SQT)
#define OFF_POS_LO (OFF_POS_HI + SPOS)
// total = 80740352 bytes (~77 MiB) -- assumed <= ws_size

extern "C" void kernel_launch(void* const* d_in, const int* in_sizes, int n_in,
                              void* d_out, int out_size, void* d_ws, size_t ws_size,
                              hipStream_t stream) {
    const float* x   = (const float*)d_in[0];
    const float* d   = (const float*)d_in[1];
    const float* Wq  = (const float*)d_in[2];
    const float* bq  = (const float*)d_in[3];
    const float* Wk  = (const float*)d_in[4];
    const float* bk  = (const float*)d_in[5];
    const float* Wv  = (const float*)d_in[6];
    const float* bv  = (const float*)d_in[7];
    const float* rh  = (const float*)d_in[8];
    const float* rw  = (const float*)d_in[9];

    char* ws = (char*)d_ws;
    u16* xt_hi = (u16*)(ws + OFF_XT_HI);
    u16* xt_lo = (u16*)(ws + OFF_XT_LO);
    u16* dt_hi = (u16*)(ws + OFF_DT_HI);
    u16* dt_lo = (u16*)(ws + OFF_DT_LO);
    u16* wq_hi = (u16*)(ws + OFF_WQ_HI);
    u16* wq_lo = (u16*)(ws + OFF_WQ_LO);
    u16* wk_hi = (u16*)(ws + OFF_WK_HI);
    u16* wk_lo = (u16*)(ws + OFF_WK_LO);
    u16* wv_hi = (u16*)(ws + OFF_WV_HI);
    u16* wv_lo = (u16*)(ws + OFF_WV_LO);
    u16* qt_hi = (u16*)(ws + OFF_QT_HI);
    u16* qt_lo = (u16*)(ws + OFF_QT_LO);
    u16* kt_hi = (u16*)(ws + OFF_KT_HI);
    u16* kt_lo = (u16*)(ws + OFF_KT_LO);
    u16* v_    = (u16*)(ws + OFF_V);
    u16* ps_hi = (u16*)(ws + OFF_POS_HI);
    u16* ps_lo = (u16*)(ws + OFF_POS_LO);

    k_split<<<1024, 256, 0, stream>>>(Wq, wq_hi, wq_lo, 512 * 512);
    k_split<<<1024, 256, 0, stream>>>(Wk, wk_hi, wk_lo, 512 * 512);
    k_split<<<1024, 256, 0, stream>>>(Wv, wv_hi, wv_lo, 512 * 512);
    k_pos<<<2048, 256, 0, stream>>>(rh, rw, ps_hi, ps_lo);
    k_tsplit<<<dim3(16, 8, 16), 256, 0, stream>>>(x, d, xt_hi, xt_lo, dt_hi, dt_lo);
    k_proj<<<dim3(4, 8, 24), 256, 0, stream>>>(xt_hi, xt_lo, dt_hi, dt_lo,
                                               wq_hi, wq_lo, wk_hi, wk_lo, wv_hi,
                                               bq, bk, bv,
                                               qt_hi, qt_lo, kt_hi, kt_lo, v_);
    k_attn<<<dim3(16, 8, 8), 256, 0, stream>>>(qt_hi, qt_lo, kt_hi, kt_lo, v_, ps_hi, ps_lo,
                                               (float*)d_out);
}

// Round 2
// 206.377 us; speedup vs baseline: 1.5560x; 1.5560x over previous
//
#include <hip/hip_runtime.h>

typedef unsigned short u16;
typedef __bf16 bf16x8 __attribute__((ext_vector_type(8)));
typedef _Float16 f16x8 __attribute__((ext_vector_type(8)));
typedef float f32x4 __attribute__((ext_vector_type(4)));
typedef float f32x16 __attribute__((ext_vector_type(16)));

#define NB 8
#define NC 512
#define NHD 8
#define DH 64
#define NN 1024

// ---- fp32 -> bf16 split helpers (RNE) ----
__device__ __forceinline__ u16 f2bf(float f) {
    union { float f; unsigned u; } v; v.f = f;
    unsigned r = v.u + 0x7fffu + ((v.u >> 16) & 1u);
    return (u16)(r >> 16);
}
__device__ __forceinline__ float bf2f(u16 h) {
    union { unsigned u; float f; } v; v.u = ((unsigned)h) << 16;
    return v.f;
}
__device__ __forceinline__ u16 f2h(float f) {
    union { _Float16 h; u16 u; } v; v.h = (_Float16)f;
    return v.u;
}

// ================= kernel 1: split a dense fp32 array into bf16 hi/lo =================
__global__ __launch_bounds__(256) void k_split(const float* __restrict__ src,
                                               u16* __restrict__ hi, u16* __restrict__ lo, int n) {
    int i = blockIdx.x * 256 + threadIdx.x;
    if (i < n) {
        float f = src[i];
        u16 h = f2bf(f);
        hi[i] = h;
        lo[i] = f2bf(f - bf2f(h));
    }
}

// ================= kernel 2: pos[h, i, d] = rel_h + rel_w  (fp16, transposed) =================
__global__ __launch_bounds__(256) void k_pos(const float* __restrict__ relh, const float* __restrict__ relw,
                                             u16* __restrict__ ph) {
    int idx = blockIdx.x * 256 + threadIdx.x;   // HEADS*N*DH = 524288 threads
    int dd = idx & 63;
    int i  = (idx >> 6) & 1023;
    int h  = idx >> 16;
    float f = relh[(h * 64 + dd) * 32 + (i & 31)] + relw[(h * 64 + dd) * 32 + (i >> 5)];
    ph[(h * 1024 + i) * 64 + dd] = f2h(f);
}

// ================= kernel 3: transpose x[b,c,n] -> xt[b,n,c] with bf16 hi/lo split =================
__global__ __launch_bounds__(256) void k_tsplit(const float* __restrict__ x, const float* __restrict__ d,
                                                u16* __restrict__ xhi, u16* __restrict__ xlo,
                                                u16* __restrict__ dhi, u16* __restrict__ dlo) {
    __shared__ float tile[64][65];
    int nb = blockIdx.x * 64;
    int cb = blockIdx.y * 64;
    int b = blockIdx.z & 7;
    int which = blockIdx.z >> 3;
    const float* src = which ? d : x;
    u16* ohi = which ? dhi : xhi;
    u16* olo = which ? dlo : xlo;
    int t = threadIdx.x;
    {
        int crow = t >> 2, n0 = (t & 3) * 16;
        const float* g = src + ((size_t)(b * NC + cb + crow)) * NN + nb + n0;
#pragma unroll
        for (int k = 0; k < 16; k += 4) {
            float4 v = *(const float4*)(g + k);
            tile[crow][n0 + k + 0] = v.x;
            tile[crow][n0 + k + 1] = v.y;
            tile[crow][n0 + k + 2] = v.z;
            tile[crow][n0 + k + 3] = v.w;
        }
    }
    __syncthreads();
    {
        int nrow = t >> 2, c0 = (t & 3) * 16;
        union { u16 s[16]; uint4 v[2]; } uh, ul;
#pragma unroll
        for (int k = 0; k < 16; ++k) {
            float f = tile[c0 + k][nrow];
            u16 hb = f2bf(f);
            uh.s[k] = hb;
            ul.s[k] = f2bf(f - bf2f(hb));
        }
        size_t oidx = ((size_t)(b * NN + nb + nrow)) * NC + cb + c0;
        *(uint4*)(ohi + oidx)     = uh.v[0];
        *(uint4*)(ohi + oidx + 8) = uh.v[1];
        *(uint4*)(olo + oidx)     = ul.v[0];
        *(uint4*)(olo + oidx + 8) = ul.v[1];
    }
}

// ================= kernel 4: projection GEMM (split-bf16 internal, fp16 outputs) =================
__global__ __launch_bounds__(256) void k_proj(
    const u16* __restrict__ xt_hi, const u16* __restrict__ xt_lo,
    const u16* __restrict__ dt_hi, const u16* __restrict__ dt_lo,
    const u16* __restrict__ wq_hi, const u16* __restrict__ wq_lo,
    const u16* __restrict__ wk_hi, const u16* __restrict__ wk_lo,
    const u16* __restrict__ wv_hi,
    const float* __restrict__ bq, const float* __restrict__ bk, const float* __restrict__ bv,
    u16* __restrict__ qt_o, u16* __restrict__ kt_o, u16* __restrict__ v_o) {
    __shared__ u16 Asm[128 * 40];
    __shared__ u16 Bsm[128 * 40];

    int p = blockIdx.z % 3;
    int b = blockIdx.z / 3;
    const u16 *Whi, *Wlo, *Xhi, *Xlo;
    const float* bias;
    u16* Oq;
    int segs;
    if (p == 0)      { Whi = wq_hi; Wlo = wq_lo; Xhi = xt_hi; Xlo = xt_lo; bias = bq; Oq = qt_o; segs = 3; }
    else if (p == 1) { Whi = wk_hi; Wlo = wk_lo; Xhi = dt_hi; Xlo = dt_lo; bias = bk; Oq = kt_o; segs = 3; }
    else             { Whi = wv_hi; Wlo = wv_hi; Xhi = dt_hi; Xlo = dt_hi; bias = bv; Oq = v_o;  segs = 1; }

    int obase = blockIdx.x * 128;
    int nbase = blockIdx.y * 128;
    int t = threadIdx.x, wave = t >> 6, lane = t & 63, quad = lane >> 4, l15 = lane & 15;
    int wr = (wave >> 1) * 64, wc = (wave & 1) * 64;

    f32x4 acc[4][4];
#pragma unroll
    for (int fo = 0; fo < 4; ++fo)
#pragma unroll
        for (int fn = 0; fn < 4; ++fn)
#pragma unroll
            for (int r = 0; r < 4; ++r) acc[fo][fn][r] = 0.f;

    for (int s = 0; s < segs; ++s) {
        const u16* Ap = (s == 1) ? Wlo : Whi;
        const u16* Bp = ((s == 2) ? Xlo : Xhi) + (size_t)b * NN * NC;
        for (int kk = 0; kk < NC; kk += 32) {
            __syncthreads();
#pragma unroll
            for (int hh = 0; hh < 2; ++hh) {
                int chunk = t + hh * 256;
                int row = chunk >> 2, cc = (chunk & 3) * 8;
                *(uint4*)&Asm[row * 40 + cc] = *(const uint4*)&Ap[(size_t)(obase + row) * NC + kk + cc];
                *(uint4*)&Bsm[row * 40 + cc] = *(const uint4*)&Bp[(size_t)(nbase + row) * NC + kk + cc];
            }
            __syncthreads();
            bf16x8 af[4], bfr[4];
#pragma unroll
            for (int fo = 0; fo < 4; ++fo) af[fo] = *(const bf16x8*)&Asm[(wr + fo * 16 + l15) * 40 + quad * 8];
#pragma unroll
            for (int fn = 0; fn < 4; ++fn) bfr[fn] = *(const bf16x8*)&Bsm[(wc + fn * 16 + l15) * 40 + quad * 8];
#pragma unroll
            for (int fo = 0; fo < 4; ++fo)
#pragma unroll
                for (int fn = 0; fn < 4; ++fn)
                    acc[fo][fn] = __builtin_amdgcn_mfma_f32_16x16x32_bf16(af[fo], bfr[fn], acc[fo][fn], 0, 0, 0);
        }
    }

#pragma unroll
    for (int fo = 0; fo < 4; ++fo) {
#pragma unroll
        for (int fn = 0; fn < 4; ++fn) {
            int o0 = obase + wr + fo * 16 + quad * 4;     // 4-aligned, never crosses a head
            int n = nbase + wc + fn * 16 + l15;
            if (p < 2) {
                union { u16 s[4]; uint2 v2; } uh;
#pragma unroll
                for (int r = 0; r < 4; ++r) uh.s[r] = f2h(acc[fo][fn][r] + bias[o0 + r]);
                int head = o0 >> 6, dd0 = o0 & 63;
                size_t idx = (((size_t)(b * NHD + head) * NN) + n) * DH + dd0;
                *(uint2*)&Oq[idx] = uh.v2;
            } else {
#pragma unroll
                for (int r = 0; r < 4; ++r) {
                    int o = o0 + r;
                    int head = o >> 6, dd = o & 63;
                    Oq[((size_t)(b * NHD + head) * DH + dd) * NN + n] = f2h(acc[fo][fn][r] + bias[o]);
                }
            }
        }
    }
}

// ================= kernel 5: fused flash attention v2 (S^T, 32x32x16 fp16 MFMA) =================
__global__ __launch_bounds__(256) void k_attn(
    const u16* __restrict__ qt, const u16* __restrict__ kt,
    const u16* __restrict__ v_, const u16* __restrict__ pos,
    float* __restrict__ out) {
    __shared__ u16 Bs[64 * 136];   // rows j: [K(64) | Q(64)] fp16, pad 8
    __shared__ u16 Vt[64 * 72];    // [d][j] fp16, pad 8
    __shared__ u16 Pt[128 * 72];   // wave-private i-strips: [i_local][j]

    int ib = blockIdx.x, head = blockIdx.y, b = blockIdx.z;
    int t = threadIdx.x, ws = t >> 6, lane = t & 63, h = lane >> 5, l31 = lane & 31;
    size_t bh = (size_t)(b * NHD + head);
    const u16* qb = qt + bh * NN * DH;
    const u16* kb = kt + bh * NN * DH;
    const u16* vb = v_ + bh * DH * NN;
    const u16* pb = pos + (size_t)head * NN * DH;
    int i0 = ib * 128;
    int iglob = i0 + ws * 32 + l31;

    // cache this wave's i-strip B-operand frags: k 0..63 = Q_i, 64..127 = Pos_i
    f16x8 qf[8];
#pragma unroll
    for (int ks = 0; ks < 4; ++ks) qf[ks] = *(const f16x8*)&qb[(size_t)iglob * DH + ks * 16 + h * 8];
#pragma unroll
    for (int ks = 4; ks < 8; ++ks) qf[ks] = *(const f16x8*)&pb[(size_t)iglob * DH + (ks - 4) * 16 + h * 8];

    f32x16 oacc[2];
#pragma unroll
    for (int df = 0; df < 2; ++df)
#pragma unroll
        for (int r = 0; r < 16; ++r) oacc[df][r] = 0.f;
    float m_ = -__builtin_inff(), l_ = 0.f;
    int ptb = ws * 32 * 72;

    for (int jc = 0; jc < NN; jc += 64) {
        __syncthreads();
#pragma unroll
        for (int u = 0; u < 4; ++u) {
            int c = u * 256 + t;
            int row = c >> 4, g = c & 15;
            const u16* src = (g < 8) ? &kb[(size_t)(jc + row) * DH + g * 8]
                                     : &qb[(size_t)(jc + row) * DH + (g - 8) * 8];
            *(uint4*)&Bs[row * 136 + g * 8] = *(const uint4*)src;
        }
#pragma unroll
        for (int u = 0; u < 2; ++u) {
            int c = u * 256 + t;
            int row = c >> 3, g = c & 7;
            *(uint4*)&Vt[row * 72 + g * 8] = *(const uint4*)&vb[(size_t)row * NN + jc + g * 8];
        }
        __syncthreads();

        // ---- S^T: 2 j-frags of 32 rows, extended K=128 over 8 ks ----
        f32x16 sacc[2];
#pragma unroll
        for (int jf = 0; jf < 2; ++jf)
#pragma unroll
            for (int r = 0; r < 16; ++r) sacc[jf][r] = 0.f;
#pragma unroll
        for (int jf = 0; jf < 2; ++jf)
#pragma unroll
            for (int ks = 0; ks < 8; ++ks) {
                f16x8 af = *(const f16x8*)&Bs[(jf * 32 + l31) * 136 + ks * 16 + h * 8];
                sacc[jf] = __builtin_amdgcn_mfma_f32_32x32x16_f16(af, qf[ks], sacc[jf], 0, 0, 0);
            }

        // ---- online softmax over j: in-lane 32 values + one cross-half shfl ----
        float mloc = -__builtin_inff();
#pragma unroll
        for (int jf = 0; jf < 2; ++jf)
#pragma unroll
            for (int r = 0; r < 16; ++r) mloc = fmaxf(mloc, sacc[jf][r]);
        mloc = fmaxf(mloc, __shfl_xor(mloc, 32));
        float mnew = fmaxf(m_, mloc);
        float alpha = __expf(m_ - mnew);
        m_ = mnew;
        float lsum = 0.f;
#pragma unroll
        for (int jf = 0; jf < 2; ++jf)
#pragma unroll
            for (int r = 0; r < 16; ++r) {
                float pv = __expf(sacc[jf][r] - mnew);
                sacc[jf][r] = pv;
                lsum += pv;
            }
        lsum += __shfl_xor(lsum, 32);
        l_ = l_ * alpha + lsum;

        // ---- P -> wave-private LDS strip Pt[i=l31][j] ----
        // lane (h,l31) holds P[i=l31][j = jf*32 + 4h + 8m + r]
#pragma unroll
        for (int jf = 0; jf < 2; ++jf)
#pragma unroll
            for (int mm = 0; mm < 4; ++mm) {
                union { _Float16 q[4]; uint2 u2; } w;
#pragma unroll
                for (int r = 0; r < 4; ++r) w.q[r] = (_Float16)sacc[jf][mm * 4 + r];
                *(uint2*)&Pt[ptb + l31 * 72 + jf * 32 + 4 * h + 8 * mm] = w.u2;
            }

        // ---- rescale O, PV: O[d,i] += V . P^T ----
#pragma unroll
        for (int df = 0; df < 2; ++df)
#pragma unroll
            for (int r = 0; r < 16; ++r) oacc[df][r] *= alpha;
#pragma unroll
        for (int jw = 0; jw < 4; ++jw) {
            f16x8 pf = *(const f16x8*)&Pt[ptb + l31 * 72 + jw * 16 + h * 8];
#pragma unroll
            for (int df = 0; df < 2; ++df) {
                f16x8 vf = *(const f16x8*)&Vt[(df * 32 + l31) * 72 + jw * 16 + h * 8];
                oacc[df] = __builtin_amdgcn_mfma_f32_32x32x16_f16(vf, pf, oacc[df], 0, 0, 0);
            }
        }
    }

    // ---- epilogue ----
    float li = 1.0f / l_;
#pragma unroll
    for (int df = 0; df < 2; ++df)
#pragma unroll
        for (int r = 0; r < 16; ++r) {
            int d = df * 32 + (r & 3) + 8 * (r >> 2) + 4 * h;
            out[((size_t)(b * NC) + head * DH + d) * NN + i0 + ws * 32 + l31] = oacc[df][r] * li;
        }
}

// ================= workspace layout (bytes) =================
#define SXT  (8u * 1024u * 512u * 2u)
#define SW   (512u * 512u * 2u)
#define SQT  SXT
#define SPOS (8u * 1024u * 64u * 2u)

#define OFF_XT_HI  (0u)
#define OFF_XT_LO  (OFF_XT_HI + SXT)
#define OFF_DT_HI  (OFF_XT_LO + SXT)
#define OFF_DT_LO  (OFF_DT_HI + SXT)
#define OFF_WQ_HI  (OFF_DT_LO + SXT)
#define OFF_WQ_LO  (OFF_WQ_HI + SW)
#define OFF_WK_HI  (OFF_WQ_LO + SW)
#define OFF_WK_LO  (OFF_WK_HI + SW)
#define OFF_WV_HI  (OFF_WK_LO + SW)
#define OFF_WV_LO  (OFF_WV_HI + SW)
#define OFF_QT    (OFF_WV_LO + SW)
#define OFF_KT    (OFF_QT + SQT)
#define OFF_V     (OFF_KT + SQT)
#define OFF_POS   (OFF_V + SQT)
// total = 4*8388608 + 6*524288 + 3*8388608 + 1048576 = 63,963,136 bytes (~61 MiB)

extern "C" void kernel_launch(void* const* d_in, const int* in_sizes, int n_in,
                              void* d_out, int out_size, void* d_ws, size_t ws_size,
                              hipStream_t stream) {
    const float* x   = (const float*)d_in[0];
    const float* d   = (const float*)d_in[1];
    const float* Wq  = (const float*)d_in[2];
    const float* bq  = (const float*)d_in[3];
    const float* Wk  = (const float*)d_in[4];
    const float* bk  = (const float*)d_in[5];
    const float* Wv  = (const float*)d_in[6];
    const float* bv  = (const float*)d_in[7];
    const float* rh  = (const float*)d_in[8];
    const float* rw  = (const float*)d_in[9];

    char* ws = (char*)d_ws;
    u16* xt_hi = (u16*)(ws + OFF_XT_HI);
    u16* xt_lo = (u16*)(ws + OFF_XT_LO);
    u16* dt_hi = (u16*)(ws + OFF_DT_HI);
    u16* dt_lo = (u16*)(ws + OFF_DT_LO);
    u16* wq_hi = (u16*)(ws + OFF_WQ_HI);
    u16* wq_lo = (u16*)(ws + OFF_WQ_LO);
    u16* wk_hi = (u16*)(ws + OFF_WK_HI);
    u16* wk_lo = (u16*)(ws + OFF_WK_LO);
    u16* wv_hi = (u16*)(ws + OFF_WV_HI);
    u16* wv_lo = (u16*)(ws + OFF_WV_LO);
    u16* qt    = (u16*)(ws + OFF_QT);
    u16* kt    = (u16*)(ws + OFF_KT);
    u16* v_    = (u16*)(ws + OFF_V);
    u16* ps    = (u16*)(ws + OFF_POS);

    k_split<<<1024, 256, 0, stream>>>(Wq, wq_hi, wq_lo, 512 * 512);
    k_split<<<1024, 256, 0, stream>>>(Wk, wk_hi, wk_lo, 512 * 512);
    k_split<<<1024, 256, 0, stream>>>(Wv, wv_hi, wv_lo, 512 * 512);
    k_pos<<<2048, 256, 0, stream>>>(rh, rw, ps);
    k_tsplit<<<dim3(16, 8, 16), 256, 0, stream>>>(x, d, xt_hi, xt_lo, dt_hi, dt_lo);
    k_proj<<<dim3(4, 8, 24), 256, 0, stream>>>(xt_hi, xt_lo, dt_hi, dt_lo,
                                               wq_hi, wq_lo, wk_hi, wk_lo, wv_hi,
                                               bq, bk, bv,
                                               qt, kt, v_);
    k_attn<<<dim3(8, 8, 8), 256, 0, stream>>>(qt, kt, v_, ps, (float*)d_out);
}

// Round 3
// 177.103 us; speedup vs baseline: 1.8132x; 1.1653x over previous
//
#include <hip/hip_runtime.h>

typedef unsigned short u16;
typedef _Float16 f16x8 __attribute__((ext_vector_type(8)));
typedef float f32x4 __attribute__((ext_vector_type(4)));
typedef float f32x16 __attribute__((ext_vector_type(16)));

#define NB 8
#define NC 512
#define NHD 8
#define DH 64
#define NN 1024

__device__ __forceinline__ u16 f2h(float f) {
    union { _Float16 h; u16 u; } v; v.h = (_Float16)f;
    return v.u;
}

// ================= kernel 1: convert the three weight matrices fp32 -> fp16 =================
__global__ __launch_bounds__(256) void k_cvt(const float* __restrict__ a, const float* __restrict__ b,
                                             const float* __restrict__ c,
                                             u16* __restrict__ oa, u16* __restrict__ ob, u16* __restrict__ oc) {
    int i = blockIdx.x * 256 + threadIdx.x;      // 262144 per matrix
    const float* src = (blockIdx.y == 0) ? a : (blockIdx.y == 1) ? b : c;
    u16* dst = (blockIdx.y == 0) ? oa : (blockIdx.y == 1) ? ob : oc;
    dst[i] = f2h(src[i]);
}

// ================= kernel 2: pos[h, i, d] = rel_h + rel_w  (fp16, transposed) =================
__global__ __launch_bounds__(256) void k_pos(const float* __restrict__ relh, const float* __restrict__ relw,
                                             u16* __restrict__ ph) {
    int idx = blockIdx.x * 256 + threadIdx.x;   // HEADS*N*DH = 524288 threads
    int dd = idx & 63;
    int i  = (idx >> 6) & 1023;
    int h  = idx >> 16;
    float f = relh[(h * 64 + dd) * 32 + (i & 31)] + relw[(h * 64 + dd) * 32 + (i >> 5)];
    ph[(h * 1024 + i) * 64 + dd] = f2h(f);
}

// ================= kernel 3: transpose x[b,c,n] -> xt[b,n,c] fp16 =================
__global__ __launch_bounds__(256) void k_t16(const float* __restrict__ x, const float* __restrict__ d,
                                             u16* __restrict__ xt, u16* __restrict__ dt) {
    __shared__ float tile[64][65];
    int nb = blockIdx.x * 64;
    int cb = blockIdx.y * 64;
    int b = blockIdx.z & 7;
    int which = blockIdx.z >> 3;
    const float* src = which ? d : x;
    u16* ot = which ? dt : xt;
    int t = threadIdx.x;
    {
        int crow = t >> 2, n0 = (t & 3) * 16;
        const float* g = src + ((size_t)(b * NC + cb + crow)) * NN + nb + n0;
#pragma unroll
        for (int k = 0; k < 16; k += 4) {
            float4 v = *(const float4*)(g + k);
            tile[crow][n0 + k + 0] = v.x;
            tile[crow][n0 + k + 1] = v.y;
            tile[crow][n0 + k + 2] = v.z;
            tile[crow][n0 + k + 3] = v.w;
        }
    }
    __syncthreads();
    {
        int nrow = t >> 2, c0 = (t & 3) * 16;
        union { u16 s[16]; uint4 v[2]; } uh;
#pragma unroll
        for (int k = 0; k < 16; ++k) uh.s[k] = f2h(tile[c0 + k][nrow]);
        size_t oidx = ((size_t)(b * NN + nb + nrow)) * NC + cb + c0;
        *(uint4*)(ot + oidx)     = uh.v[0];
        *(uint4*)(ot + oidx + 8) = uh.v[1];
    }
}

// ================= kernel 4: projection GEMM, single-pass fp16, global_load_lds staging =================
// y[o][n] = sum_c W[o][c] x^T[n][c] + bias[o]; 128x128 tile, BK=32, m97-style.
__global__ __launch_bounds__(256) void k_proj(
    const u16* __restrict__ xt, const u16* __restrict__ dt,
    const u16* __restrict__ wq, const u16* __restrict__ wk, const u16* __restrict__ wv,
    const float* __restrict__ bq, const float* __restrict__ bk, const float* __restrict__ bv,
    u16* __restrict__ qt_o, u16* __restrict__ kt_o, u16* __restrict__ v_o) {
    __shared__ u16 Asm[128 * 32];   // UNPADDED: required by global_load_lds lane mapping
    __shared__ u16 Bsm[128 * 32];

    int p = blockIdx.z % 3;
    int b = blockIdx.z / 3;
    const u16 *Ap, *Bp;
    const float* bias;
    u16* Oq;
    if (p == 0)      { Ap = wq; Bp = xt; bias = bq; Oq = qt_o; }
    else if (p == 1) { Ap = wk; Bp = dt; bias = bk; Oq = kt_o; }
    else             { Ap = wv; Bp = dt; bias = bv; Oq = v_o; }
    Bp += (size_t)b * NN * NC;

    int obase = blockIdx.x * 128;
    int nbase = blockIdx.y * 128;
    int t = threadIdx.x, wave = t >> 6, quad = (t & 63) >> 4, l15 = t & 15;
    int wr = (wave >> 1) * 64, wc = (wave & 1) * 64;

    f32x4 acc[4][4];
#pragma unroll
    for (int fo = 0; fo < 4; ++fo)
#pragma unroll
        for (int fn = 0; fn < 4; ++fn)
#pragma unroll
            for (int r = 0; r < 4; ++r) acc[fo][fn][r] = 0.f;

    for (int kk = 0; kk < NC; kk += 32) {
        __syncthreads();   // previous iter's frag reads complete before overwrite
#pragma unroll
        for (int u = 0; u < 2; ++u) {
            int c = u * 256 + t;               // chunk id: 16B granules, lane-ordered per wave
            int row = c >> 2, part = c & 3;
            __builtin_amdgcn_global_load_lds(
                (const __attribute__((address_space(1))) void*)(Ap + (size_t)(obase + row) * NC + kk + part * 8),
                (__attribute__((address_space(3))) void*)(Asm + (size_t)(u * 256 + wave * 64) * 8), 16, 0, 0);
            __builtin_amdgcn_global_load_lds(
                (const __attribute__((address_space(1))) void*)(Bp + (size_t)(nbase + row) * NC + kk + part * 8),
                (__attribute__((address_space(3))) void*)(Bsm + (size_t)(u * 256 + wave * 64) * 8), 16, 0, 0);
        }
        __syncthreads();   // drains vmcnt: LDS tiles valid

        f16x8 af[4], bfr[4];
#pragma unroll
        for (int fo = 0; fo < 4; ++fo) af[fo] = *(const f16x8*)&Asm[(wr + fo * 16 + l15) * 32 + quad * 8];
#pragma unroll
        for (int fn = 0; fn < 4; ++fn) bfr[fn] = *(const f16x8*)&Bsm[(wc + fn * 16 + l15) * 32 + quad * 8];
#pragma unroll
        for (int fo = 0; fo < 4; ++fo)
#pragma unroll
            for (int fn = 0; fn < 4; ++fn)
                acc[fo][fn] = __builtin_amdgcn_mfma_f32_16x16x32_f16(af[fo], bfr[fn], acc[fo][fn], 0, 0, 0);
    }

#pragma unroll
    for (int fo = 0; fo < 4; ++fo) {
#pragma unroll
        for (int fn = 0; fn < 4; ++fn) {
            int o0 = obase + wr + fo * 16 + quad * 4;     // 4-aligned, never crosses a head
            int n = nbase + wc + fn * 16 + l15;
            if (p < 2) {
                union { u16 s[4]; uint2 v2; } uh;
#pragma unroll
                for (int r = 0; r < 4; ++r) uh.s[r] = f2h(acc[fo][fn][r] + bias[o0 + r]);
                int head = o0 >> 6, dd0 = o0 & 63;
                size_t idx = (((size_t)(b * NHD + head) * NN) + n) * DH + dd0;
                *(uint2*)&Oq[idx] = uh.v2;
            } else {
#pragma unroll
                for (int r = 0; r < 4; ++r) {
                    int o = o0 + r;
                    int head = o >> 6, dd = o & 63;
                    Oq[((size_t)(b * NHD + head) * DH + dd) * NN + n] = f2h(acc[fo][fn][r] + bias[o]);
                }
            }
        }
    }
}

// ================= kernel 5: fused flash attention (S^T, 32x32x16 fp16 MFMA) =================
__global__ __launch_bounds__(256) void k_attn(
    const u16* __restrict__ qt, const u16* __restrict__ kt,
    const u16* __restrict__ v_, const u16* __restrict__ pos,
    float* __restrict__ out) {
    __shared__ u16 Bs[64 * 136];   // rows j: [K(64) | Q(64)] fp16, pad 8
    __shared__ u16 Vt[64 * 72];    // [d][j] fp16, pad 8
    __shared__ u16 Pt[128 * 72];   // wave-private i-strips: [i_local][j]

    int ib = blockIdx.x, head = blockIdx.y, b = blockIdx.z;
    int t = threadIdx.x, ws = t >> 6, lane = t & 63, h = lane >> 5, l31 = lane & 31;
    size_t bh = (size_t)(b * NHD + head);
    const u16* qb = qt + bh * NN * DH;
    const u16* kb = kt + bh * NN * DH;
    const u16* vb = v_ + bh * DH * NN;
    const u16* pb = pos + (size_t)head * NN * DH;
    int i0 = ib * 128;
    int iglob = i0 + ws * 32 + l31;

    // cache this wave's i-strip B-operand frags: k 0..63 = Q_i, 64..127 = Pos_i
    f16x8 qf[8];
#pragma unroll
    for (int ks = 0; ks < 4; ++ks) qf[ks] = *(const f16x8*)&qb[(size_t)iglob * DH + ks * 16 + h * 8];
#pragma unroll
    for (int ks = 4; ks < 8; ++ks) qf[ks] = *(const f16x8*)&pb[(size_t)iglob * DH + (ks - 4) * 16 + h * 8];

    f32x16 oacc[2];
#pragma unroll
    for (int df = 0; df < 2; ++df)
#pragma unroll
        for (int r = 0; r < 16; ++r) oacc[df][r] = 0.f;
    float m_ = -__builtin_inff(), l_ = 0.f;
    int ptb = ws * 32 * 72;

    for (int jc = 0; jc < NN; jc += 64) {
        __syncthreads();
#pragma unroll
        for (int u = 0; u < 4; ++u) {
            int c = u * 256 + t;
            int row = c >> 4, g = c & 15;
            const u16* src = (g < 8) ? &kb[(size_t)(jc + row) * DH + g * 8]
                                     : &qb[(size_t)(jc + row) * DH + (g - 8) * 8];
            *(uint4*)&Bs[row * 136 + g * 8] = *(const uint4*)src;
        }
#pragma unroll
        for (int u = 0; u < 2; ++u) {
            int c = u * 256 + t;
            int row = c >> 3, g = c & 7;
            *(uint4*)&Vt[row * 72 + g * 8] = *(const uint4*)&vb[(size_t)row * NN + jc + g * 8];
        }
        __syncthreads();

        // ---- S^T: 2 j-frags of 32 rows, extended K=128 over 8 ks ----
        f32x16 sacc[2];
#pragma unroll
        for (int jf = 0; jf < 2; ++jf)
#pragma unroll
            for (int r = 0; r < 16; ++r) sacc[jf][r] = 0.f;
#pragma unroll
        for (int jf = 0; jf < 2; ++jf)
#pragma unroll
            for (int ks = 0; ks < 8; ++ks) {
                f16x8 af = *(const f16x8*)&Bs[(jf * 32 + l31) * 136 + ks * 16 + h * 8];
                sacc[jf] = __builtin_amdgcn_mfma_f32_32x32x16_f16(af, qf[ks], sacc[jf], 0, 0, 0);
            }

        // ---- online softmax over j: in-lane 32 values + one cross-half shfl ----
        float mloc = -__builtin_inff();
#pragma unroll
        for (int jf = 0; jf < 2; ++jf)
#pragma unroll
            for (int r = 0; r < 16; ++r) mloc = fmaxf(mloc, sacc[jf][r]);
        mloc = fmaxf(mloc, __shfl_xor(mloc, 32));
        float mnew = fmaxf(m_, mloc);
        float alpha = __expf(m_ - mnew);
        m_ = mnew;
        float lsum = 0.f;
#pragma unroll
        for (int jf = 0; jf < 2; ++jf)
#pragma unroll
            for (int r = 0; r < 16; ++r) {
                float pv = __expf(sacc[jf][r] - mnew);
                sacc[jf][r] = pv;
                lsum += pv;
            }
        lsum += __shfl_xor(lsum, 32);
        l_ = l_ * alpha + lsum;

        // ---- P -> wave-private LDS strip Pt[i=l31][j] ----
#pragma unroll
        for (int jf = 0; jf < 2; ++jf)
#pragma unroll
            for (int mm = 0; mm < 4; ++mm) {
                union { _Float16 q[4]; uint2 u2; } w;
#pragma unroll
                for (int r = 0; r < 4; ++r) w.q[r] = (_Float16)sacc[jf][mm * 4 + r];
                *(uint2*)&Pt[ptb + l31 * 72 + jf * 32 + 4 * h + 8 * mm] = w.u2;
            }

        // ---- rescale O, PV: O[d,i] += V . P^T ----
#pragma unroll
        for (int df = 0; df < 2; ++df)
#pragma unroll
            for (int r = 0; r < 16; ++r) oacc[df][r] *= alpha;
#pragma unroll
        for (int jw = 0; jw < 4; ++jw) {
            f16x8 pf = *(const f16x8*)&Pt[ptb + l31 * 72 + jw * 16 + h * 8];
#pragma unroll
            for (int df = 0; df < 2; ++df) {
                f16x8 vf = *(const f16x8*)&Vt[(df * 32 + l31) * 72 + jw * 16 + h * 8];
                oacc[df] = __builtin_amdgcn_mfma_f32_32x32x16_f16(vf, pf, oacc[df], 0, 0, 0);
            }
        }
    }

    // ---- epilogue ----
    float li = 1.0f / l_;
#pragma unroll
    for (int df = 0; df < 2; ++df)
#pragma unroll
        for (int r = 0; r < 16; ++r) {
            int d = df * 32 + (r & 3) + 8 * (r >> 2) + 4 * h;
            out[((size_t)(b * NC) + head * DH + d) * NN + i0 + ws * 32 + l31] = oacc[df][r] * li;
        }
}

// ================= workspace layout (bytes) =================
#define SXT  (8u * 1024u * 512u * 2u)      /* 8 MB: [B,N,C] fp16 */
#define SW   (512u * 512u * 2u)
#define SQT  SXT
#define SPOS (8u * 1024u * 64u * 2u)

#define OFF_XT   (0u)
#define OFF_DT   (OFF_XT + SXT)
#define OFF_WQ   (OFF_DT + SXT)
#define OFF_WK   (OFF_WQ + SW)
#define OFF_WV   (OFF_WK + SW)
#define OFF_QT   (OFF_WV + SW)
#define OFF_KT   (OFF_QT + SQT)
#define OFF_V    (OFF_KT + SQT)
#define OFF_POS  (OFF_V + SQT)
// total = 5*8388608 + 3*524288 + 1048576 = 44,564,480 bytes (~42.5 MiB)

extern "C" void kernel_launch(void* const* d_in, const int* in_sizes, int n_in,
                              void* d_out, int out_size, void* d_ws, size_t ws_size,
                              hipStream_t stream) {
    const float* x   = (const float*)d_in[0];
    const float* d   = (const float*)d_in[1];
    const float* Wq  = (const float*)d_in[2];
    const float* bq  = (const float*)d_in[3];
    const float* Wk  = (const float*)d_in[4];
    const float* bk  = (const float*)d_in[5];
    const float* Wv  = (const float*)d_in[6];
    const float* bv  = (const float*)d_in[7];
    const float* rh  = (const float*)d_in[8];
    const float* rw  = (const float*)d_in[9];

    char* ws = (char*)d_ws;
    u16* xt = (u16*)(ws + OFF_XT);
    u16* dt = (u16*)(ws + OFF_DT);
    u16* wq = (u16*)(ws + OFF_WQ);
    u16* wk = (u16*)(ws + OFF_WK);
    u16* wv = (u16*)(ws + OFF_WV);
    u16* qt = (u16*)(ws + OFF_QT);
    u16* kt = (u16*)(ws + OFF_KT);
    u16* v_ = (u16*)(ws + OFF_V);
    u16* ps = (u16*)(ws + OFF_POS);

    k_cvt<<<dim3(1024, 3), 256, 0, stream>>>(Wq, Wk, Wv, wq, wk, wv);
    k_pos<<<2048, 256, 0, stream>>>(rh, rw, ps);
    k_t16<<<dim3(16, 8, 16), 256, 0, stream>>>(x, d, xt, dt);
    k_proj<<<dim3(4, 8, 24), 256, 0, stream>>>(xt, dt, wq, wk, wv, bq, bk, bv, qt, kt, v_);
    k_attn<<<dim3(8, 8, 8), 256, 0, stream>>>(qt, kt, v_, ps, (float*)d_out);
}

// Round 5
// 166.779 us; speedup vs baseline: 1.9255x; 1.0619x over previous
//
#include <hip/hip_runtime.h>

typedef unsigned short u16;
typedef _Float16 f16x8 __attribute__((ext_vector_type(8)));
typedef __fp16 hf16x2 __attribute__((ext_vector_type(2)));
typedef float f32x4 __attribute__((ext_vector_type(4)));
typedef float f32x16 __attribute__((ext_vector_type(16)));

#define NB 8
#define NC 512
#define NHD 8
#define DH 64
#define NN 1024
#define LOG2E 1.4426950408889634f

__device__ __forceinline__ u16 f2h(float f) {
    union { _Float16 h; u16 u; } v; v.h = (_Float16)f;
    return v.u;
}

// ================= kernel 1: fused prep =================
// blocks [0,2048): transpose x/d [b,c,n] -> [b,n,c] fp16
// blocks [2048,5120): convert Wq/Wk/Wv fp32 -> fp16
// blocks [5120,7168): pos[h,i,d] = rel_h + rel_w fp16
__global__ __launch_bounds__(256) void k_prep(
    const float* __restrict__ x, const float* __restrict__ d,
    const float* __restrict__ Wq, const float* __restrict__ Wk, const float* __restrict__ Wv,
    const float* __restrict__ relh, const float* __restrict__ relw,
    u16* __restrict__ xt, u16* __restrict__ dt,
    u16* __restrict__ wq, u16* __restrict__ wk, u16* __restrict__ wv,
    u16* __restrict__ ps) {
    __shared__ float tile[64][65];
    int id = blockIdx.x, t = threadIdx.x;
    if (id < 2048) {
        // ---- transpose+cvt ----
        int nb = (id & 15) * 64;
        int cb = ((id >> 4) & 7) * 64;
        int z = id >> 7;
        int b = z & 7;
        const float* src = (z >> 3) ? d : x;
        u16* ot = (z >> 3) ? dt : xt;
        {
            int crow = t >> 2, n0 = (t & 3) * 16;
            const float* g = src + ((size_t)(b * NC + cb + crow)) * NN + nb + n0;
#pragma unroll
            for (int k = 0; k < 16; k += 4) {
                float4 v = *(const float4*)(g + k);
                tile[crow][n0 + k + 0] = v.x;
                tile[crow][n0 + k + 1] = v.y;
                tile[crow][n0 + k + 2] = v.z;
                tile[crow][n0 + k + 3] = v.w;
            }
        }
        __syncthreads();
        {
            int nrow = t >> 2, c0 = (t & 3) * 16;
            union { u16 s[16]; uint4 v[2]; } uh;
#pragma unroll
            for (int k = 0; k < 16; ++k) uh.s[k] = f2h(tile[c0 + k][nrow]);
            size_t oidx = ((size_t)(b * NN + nb + nrow)) * NC + cb + c0;
            *(uint4*)(ot + oidx)     = uh.v[0];
            *(uint4*)(ot + oidx + 8) = uh.v[1];
        }
    } else if (id < 5120) {
        int j = id - 2048;
        int m = j >> 10;
        int i = (j & 1023) * 256 + t;
        const float* src = (m == 0) ? Wq : (m == 1) ? Wk : Wv;
        u16* dst = (m == 0) ? wq : (m == 1) ? wk : wv;
        dst[i] = f2h(src[i]);
    } else {
        int idx = (id - 5120) * 256 + t;
        int dd = idx & 63;
        int i  = (idx >> 6) & 1023;
        int h  = idx >> 16;
        float f = relh[(h * 64 + dd) * 32 + (i & 31)] + relw[(h * 64 + dd) * 32 + (i >> 5)];
        ps[(h * 1024 + i) * 64 + dd] = f2h(f);
    }
}

// ================= kernel 2: projection GEMM, fp16, global_load_lds staging =================
// q output is PRE-SCALED by log2(e) (softmax runs in exp2 domain; both S terms
// carry exactly one factor of q, so S arrives scaled by log2e).
__global__ __launch_bounds__(256) void k_proj(
    const u16* __restrict__ xt, const u16* __restrict__ dt,
    const u16* __restrict__ wq, const u16* __restrict__ wk, const u16* __restrict__ wv,
    const float* __restrict__ bq, const float* __restrict__ bk, const float* __restrict__ bv,
    u16* __restrict__ qt_o, u16* __restrict__ kt_o, u16* __restrict__ v_o) {
    __shared__ u16 Asm[128 * 32];   // UNPADDED: required by global_load_lds lane mapping
    __shared__ u16 Bsm[128 * 32];

    int p = blockIdx.z % 3;
    int b = blockIdx.z / 3;
    const u16 *Ap, *Bp;
    const float* bias;
    u16* Oq;
    if (p == 0)      { Ap = wq; Bp = xt; bias = bq; Oq = qt_o; }
    else if (p == 1) { Ap = wk; Bp = dt; bias = bk; Oq = kt_o; }
    else             { Ap = wv; Bp = dt; bias = bv; Oq = v_o; }
    Bp += (size_t)b * NN * NC;
    float oscale = (p == 0) ? LOG2E : 1.0f;

    int obase = blockIdx.x * 128;
    int nbase = blockIdx.y * 128;
    int t = threadIdx.x, wave = t >> 6, quad = (t & 63) >> 4, l15 = t & 15;
    int wr = (wave >> 1) * 64, wc = (wave & 1) * 64;

    f32x4 acc[4][4];
#pragma unroll
    for (int fo = 0; fo < 4; ++fo)
#pragma unroll
        for (int fn = 0; fn < 4; ++fn)
#pragma unroll
            for (int r = 0; r < 4; ++r) acc[fo][fn][r] = 0.f;

    for (int kk = 0; kk < NC; kk += 32) {
        __syncthreads();
#pragma unroll
        for (int u = 0; u < 2; ++u) {
            int c = u * 256 + t;
            int row = c >> 2, part = c & 3;
            __builtin_amdgcn_global_load_lds(
                (const __attribute__((address_space(1))) void*)(Ap + (size_t)(obase + row) * NC + kk + part * 8),
                (__attribute__((address_space(3))) void*)(Asm + (size_t)(u * 256 + wave * 64) * 8), 16, 0, 0);
            __builtin_amdgcn_global_load_lds(
                (const __attribute__((address_space(1))) void*)(Bp + (size_t)(nbase + row) * NC + kk + part * 8),
                (__attribute__((address_space(3))) void*)(Bsm + (size_t)(u * 256 + wave * 64) * 8), 16, 0, 0);
        }
        __syncthreads();

        f16x8 af[4], bfr[4];
#pragma unroll
        for (int fo = 0; fo < 4; ++fo) af[fo] = *(const f16x8*)&Asm[(wr + fo * 16 + l15) * 32 + quad * 8];
#pragma unroll
        for (int fn = 0; fn < 4; ++fn) bfr[fn] = *(const f16x8*)&Bsm[(wc + fn * 16 + l15) * 32 + quad * 8];
#pragma unroll
        for (int fo = 0; fo < 4; ++fo)
#pragma unroll
            for (int fn = 0; fn < 4; ++fn)
                acc[fo][fn] = __builtin_amdgcn_mfma_f32_16x16x32_f16(af[fo], bfr[fn], acc[fo][fn], 0, 0, 0);
    }

#pragma unroll
    for (int fo = 0; fo < 4; ++fo) {
#pragma unroll
        for (int fn = 0; fn < 4; ++fn) {
            int o0 = obase + wr + fo * 16 + quad * 4;     // 4-aligned, never crosses a head
            int n = nbase + wc + fn * 16 + l15;
            if (p < 2) {
                union { u16 s[4]; uint2 v2; } uh;
#pragma unroll
                for (int r = 0; r < 4; ++r) uh.s[r] = f2h((acc[fo][fn][r] + bias[o0 + r]) * oscale);
                int head = o0 >> 6, dd0 = o0 & 63;
                size_t idx = (((size_t)(b * NHD + head) * NN) + n) * DH + dd0;
                *(uint2*)&Oq[idx] = uh.v2;
            } else {
#pragma unroll
                for (int r = 0; r < 4; ++r) {
                    int o = o0 + r;
                    int head = o >> 6, dd = o & 63;
                    Oq[((size_t)(b * NHD + head) * DH + dd) * NN + n] = f2h(acc[fo][fn][r] + bias[o]);
                }
            }
        }
    }
}

// ================= kernel 3: fused flash attention v3 =================
// S^T, 32x32x16 fp16 MFMA, 128-j chunks, exp2-domain softmax, XCD-swizzled grid.
__global__ __launch_bounds__(256, 2) void k_attn(
    const u16* __restrict__ qt, const u16* __restrict__ kt,
    const u16* __restrict__ v_, const u16* __restrict__ pos,
    float* __restrict__ out) {
    __shared__ u16 Bs[128 * 132];      // rows j: [K(64) | Q(64)], pad 4 (2-way = free)
    __shared__ u16 Vt[64 * 132];       // [d][j 128], pad 4
    __shared__ u16 Pt[4 * 32 * 68];    // wave-private [i 32][j 64] strips, pad 4

    // XCD swizzle: all 8 i-blocks of group g=(b,head) land on XCD g%8
    int n = blockIdx.x;
    int g = n & 63;
    int ib = n >> 6;
    int head = g & 7, b = g >> 3;

    int t = threadIdx.x, ws = t >> 6, lane = t & 63, h = lane >> 5, l31 = lane & 31;
    size_t bh = (size_t)(b * NHD + head);
    const u16* qb = qt + bh * NN * DH;
    const u16* kb = kt + bh * NN * DH;
    const u16* vb = v_ + bh * DH * NN;
    const u16* pb = pos + (size_t)head * NN * DH;
    int i0 = ib * 128;
    int iglob = i0 + ws * 32 + l31;

    // wave-private B-operand frags: k 0..63 = q_i (pre-scaled by log2e), 64..127 = pos_i
    f16x8 qf[8];
#pragma unroll
    for (int ks = 0; ks < 4; ++ks) qf[ks] = *(const f16x8*)&qb[(size_t)iglob * DH + ks * 16 + h * 8];
#pragma unroll
    for (int ks = 4; ks < 8; ++ks) qf[ks] = *(const f16x8*)&pb[(size_t)iglob * DH + (ks - 4) * 16 + h * 8];

    f32x16 oacc[2];
#pragma unroll
    for (int df = 0; df < 2; ++df)
#pragma unroll
        for (int r = 0; r < 16; ++r) oacc[df][r] = 0.f;
    float m_ = -__builtin_inff(), l_ = 0.f;
    int ptb = ws * 32 * 68;

    for (int jc = 0; jc < NN; jc += 128) {
        __syncthreads();
        // stage Bs: 128 rows x 16 chunks = 2048, 8/thread
#pragma unroll
        for (int u = 0; u < 8; ++u) {
            int c = u * 256 + t;
            int row = c >> 4, gg = c & 15;
            const u16* src = (gg < 8) ? &kb[(size_t)(jc + row) * DH + gg * 8]
                                      : &qb[(size_t)(jc + row) * DH + (gg - 8) * 8];
            *(uint4*)&Bs[row * 132 + gg * 8] = *(const uint4*)src;
        }
        // stage Vt: 64 rows x 16 chunks = 1024, 4/thread
#pragma unroll
        for (int u = 0; u < 4; ++u) {
            int c = u * 256 + t;
            int row = c >> 4, gg = c & 15;
            *(uint4*)&Vt[row * 132 + gg * 8] = *(const uint4*)&vb[(size_t)row * NN + jc + gg * 8];
        }
        __syncthreads();

        // ---- S^T: 4 j-frags of 32 rows, extended K=128 over 8 ks ----
        f32x16 sacc[4];
#pragma unroll
        for (int jf = 0; jf < 4; ++jf)
#pragma unroll
            for (int r = 0; r < 16; ++r) sacc[jf][r] = 0.f;
#pragma unroll
        for (int jf = 0; jf < 4; ++jf)
#pragma unroll
            for (int ks = 0; ks < 8; ++ks) {
                f16x8 af = *(const f16x8*)&Bs[(jf * 32 + l31) * 132 + ks * 16 + h * 8];
                sacc[jf] = __builtin_amdgcn_mfma_f32_32x32x16_f16(af, qf[ks], sacc[jf], 0, 0, 0);
            }

        // ---- online softmax over 128 j (exp2 domain; S is pre-scaled by log2e) ----
        float mloc = -__builtin_inff();
#pragma unroll
        for (int jf = 0; jf < 4; ++jf)
#pragma unroll
            for (int r = 0; r < 16; ++r) mloc = fmaxf(mloc, sacc[jf][r]);
        mloc = fmaxf(mloc, __shfl_xor(mloc, 32));
        if (__any(mloc > m_)) {
            float mnew = fmaxf(m_, mloc);
            float alpha = __builtin_amdgcn_exp2f(m_ - mnew);
            m_ = mnew;
#pragma unroll
            for (int df = 0; df < 2; ++df)
#pragma unroll
                for (int r = 0; r < 16; ++r) oacc[df][r] *= alpha;
            l_ *= alpha;
        }
        float lsum = 0.f;
#pragma unroll
        for (int jf = 0; jf < 4; ++jf)
#pragma unroll
            for (int r = 0; r < 16; ++r) {
                float pv = __builtin_amdgcn_exp2f(sacc[jf][r] - m_);
                sacc[jf][r] = pv;
                lsum += pv;
            }
        lsum += __shfl_xor(lsum, 32);
        l_ += lsum;

        // ---- P->Pt (wave-private, no barrier) + PV, in two 64-j halves ----
#pragma unroll
        for (int half = 0; half < 2; ++half) {
#pragma unroll
            for (int jf = 0; jf < 2; ++jf) {
                int jfg = half * 2 + jf;
#pragma unroll
                for (int mm = 0; mm < 4; ++mm) {
                    union { hf16x2 v; unsigned u; } p0, p1;
                    p0.v = __builtin_amdgcn_cvt_pkrtz(sacc[jfg][mm * 4 + 0], sacc[jfg][mm * 4 + 1]);
                    p1.v = __builtin_amdgcn_cvt_pkrtz(sacc[jfg][mm * 4 + 2], sacc[jfg][mm * 4 + 3]);
                    uint2 w; w.x = p0.u; w.y = p1.u;
                    *(uint2*)&Pt[ptb + l31 * 68 + jf * 32 + 4 * h + 8 * mm] = w;
                }
            }
#pragma unroll
            for (int jw = 0; jw < 4; ++jw) {
                f16x8 pf = *(const f16x8*)&Pt[ptb + l31 * 68 + jw * 16 + h * 8];
#pragma unroll
                for (int df = 0; df < 2; ++df) {
                    f16x8 vf = *(const f16x8*)&Vt[(df * 32 + l31) * 132 + half * 64 + jw * 16 + h * 8];
                    oacc[df] = __builtin_amdgcn_mfma_f32_32x32x16_f16(vf, pf, oacc[df], 0, 0, 0);
                }
            }
        }
    }

    // ---- epilogue ----
    float li = 1.0f / l_;
#pragma unroll
    for (int df = 0; df < 2; ++df)
#pragma unroll
        for (int r = 0; r < 16; ++r) {
            int dd = df * 32 + (r & 3) + 8 * (r >> 2) + 4 * h;
            out[((size_t)(b * NC) + head * DH + dd) * NN + i0 + ws * 32 + l31] = oacc[df][r] * li;
        }
}

// ================= workspace layout (bytes) =================
#define SXT  (8u * 1024u * 512u * 2u)      /* 8 MB: [B,N,C] fp16 */
#define SW   (512u * 512u * 2u)
#define SQT  SXT
#define SPOS (8u * 1024u * 64u * 2u)

#define OFF_XT   (0u)
#define OFF_DT   (OFF_XT + SXT)
#define OFF_WQ   (OFF_DT + SXT)
#define OFF_WK   (OFF_WQ + SW)
#define OFF_WV   (OFF_WK + SW)
#define OFF_QT   (OFF_WV + SW)
#define OFF_KT   (OFF_QT + SQT)
#define OFF_V    (OFF_KT + SQT)
#define OFF_POS  (OFF_V + SQT)
// total = 5*8388608 + 3*524288 + 1048576 = 44,564,480 bytes (~42.5 MiB)

extern "C" void kernel_launch(void* const* d_in, const int* in_sizes, int n_in,
                              void* d_out, int out_size, void* d_ws, size_t ws_size,
                              hipStream_t stream) {
    const float* x   = (const float*)d_in[0];
    const float* d   = (const float*)d_in[1];
    const float* Wq  = (const float*)d_in[2];
    const float* bq  = (const float*)d_in[3];
    const float* Wk  = (const float*)d_in[4];
    const float* bk  = (const float*)d_in[5];
    const float* Wv  = (const float*)d_in[6];
    const float* bv  = (const float*)d_in[7];
    const float* rh  = (const float*)d_in[8];
    const float* rw  = (const float*)d_in[9];

    char* ws = (char*)d_ws;
    u16* xt = (u16*)(ws + OFF_XT);
    u16* dt = (u16*)(ws + OFF_DT);
    u16* wq = (u16*)(ws + OFF_WQ);
    u16* wk = (u16*)(ws + OFF_WK);
    u16* wv = (u16*)(ws + OFF_WV);
    u16* qt = (u16*)(ws + OFF_QT);
    u16* kt = (u16*)(ws + OFF_KT);
    u16* v_ = (u16*)(ws + OFF_V);
    u16* ps = (u16*)(ws + OFF_POS);

    k_prep<<<7168, 256, 0, stream>>>(x, d, Wq, Wk, Wv, rh, rw, xt, dt, wq, wk, wv, ps);
    k_proj<<<dim3(4, 8, 24), 256, 0, stream>>>(xt, dt, wq, wk, wv, bq, bk, bv, qt, kt, v_);
    k_attn<<<512, 256, 0, stream>>>(qt, kt, v_, ps, (float*)d_out);
}